// Round 14
// baseline (1182.747 us; speedup 1.0000x reference)
//
#include <hip/hip_runtime.h>
#include <stdio.h>

// ---------------------------------------------------------------------------
// Masked-LSTM LM:  out = softmax(states @ Wd + bd)
//
// Round-14: tagged COALESCED entries - one L2 round-trip = sync + data.
//  * r13 proved coalescing fixed L2 request amplification (3.47->1.12ms).
//    Remaining chain had 3 L2 RTs: store-ack (vmcnt) + flag poll + data.
//  * Entry = 16B {4 f16 h, tag=t+1, pad}: ONE store instruction => tag
//    rides atomically with payload (r7-proven). Layout
//    ent[bg][ws][l4][kk][hf][b16] => consumer lane stride 16B; 8 loads at
//    offset kk*512+hf*256 each 64x16B contiguous (fully coalesced).
//  * Consumer polls the tagged entries directly (sc0 sc1 = L1-bypass,
//    served fresh by local-XCD L2 dirty lines, r12-proven): common case
//    ONE RT for sync+data. No flags, no producer vmcnt.
//  * Exact-tag spin is deadlock-free: producer writes tag t+2 into a
//    parity buffer only after its step-t+1 read completed, which needs
//    ALL blocks' h_{t+1} signals, which need each consumer block's
//    barrier AFTER all its waves read tag-t. Tags never exceed expected.
//  * Election (r6-r13): fast (same-XCD, plain producer stores) vs slow
//    (device-scope sc0 sc1 stores). Poll identical in both.
//  * Canary: absmax must stay exactly ~6.103516e-5.
// ---------------------------------------------------------------------------

typedef _Float16 f16;
typedef f16 f16x8 __attribute__((ext_vector_type(8)));
typedef f16 f16x4 __attribute__((ext_vector_type(4)));
typedef float f32x4 __attribute__((ext_vector_type(4)));
typedef unsigned int u32;
typedef u32 u32x4 __attribute__((ext_vector_type(4)));

static constexpr int V = 128, E = 256, H = 1024, NB = 128, T = 512, FH = 4096;

// workspace layout (bytes)
static constexpr size_t OFF_CTRL = 0;        // [0]=initctr, [8..15]=xcdcnt
static constexpr size_t SZ_CTRL  = 4096;
static constexpr size_t OFF_HT0  = SZ_CTRL;  // tagged entries, parity 0
static constexpr size_t SZ_HT    = (size_t)32768 * 16;         // 512 KB
static constexpr size_t OFF_HT1  = OFF_HT0 + SZ_HT;
static constexpr size_t OFF_EMBW = OFF_HT1 + SZ_HT;            // 2 MB f32
static constexpr size_t SZ_EMBW  = (size_t)V * FH * 4;
static constexpr size_t OFF_UF   = OFF_EMBW + SZ_EMBW;         // 8 MB f16
static constexpr size_t SZ_UF    = (size_t)H * FH * 2;
static constexpr size_t OFF_WD   = OFF_UF + SZ_UF;             // 256 KB f16
static constexpr size_t SZ_WD    = (size_t)H * V * 2;
static constexpr size_t OFF_ST   = OFF_WD + SZ_WD;             // 128 MB f16
static constexpr size_t SZ_ST    = (size_t)NB * T * H * 2;
static constexpr size_t WS_NEED  = OFF_ST + SZ_ST;             // ~139 MB

// ---------------------------------------------------------------------------
__device__ __forceinline__ float fast_sigmoid(float x) {
  return __builtin_amdgcn_rcpf(1.f + __expf(-x));
}
__device__ __forceinline__ float fast_tanh(float x) {
  const float e = __expf(2.f * x);
  return (e - 1.f) * __builtin_amdgcn_rcpf(e + 1.f);
}

// ---------------------------------------------------------------------------
// embW[v][j] = b[j] + sum_e emb[v][e] * W[e][j]
__global__ void prep_embW(const float* __restrict__ emb, const float* __restrict__ W,
                          const float* __restrict__ bias, float* __restrict__ embW) {
  const int j  = blockIdx.x * 16 + (threadIdx.x & 15);
  const int vg = threadIdx.x >> 4;
  float a[8];
  const float bj = bias[j];
#pragma unroll
  for (int r = 0; r < 8; ++r) a[r] = bj;
  for (int e = 0; e < E; ++e) {
    const float wv = W[(size_t)e * FH + j];
#pragma unroll
    for (int r = 0; r < 8; ++r) a[r] += emb[(size_t)(vg * 8 + r) * E + e] * wv;
  }
#pragma unroll
  for (int r = 0; r < 8; ++r) embW[(size_t)(vg * 8 + r) * FH + j] = a[r];
}

// ---------------------------------------------------------------------------
// U (f32 [1024][4096]) -> fp16 B-fragment chunks, coalesced reads (r6-proven).
// chunk = (((cg*8+w)*8+nt)*4+kk)*64 + l4s*16 + l15, element es, where
//   k = w*128+kk*32+l4s*8+es;  j = (nt>>1)*1024 + cg*32 + (nt&1)*16 + l15
__global__ void prep_U(const float* __restrict__ U, f16* __restrict__ uf) {
  const int q  = blockIdx.x * 256 + threadIdx.x;      // 0..524287
  const int k  = q >> 9;
  const int j0 = (q & 511) * 8;
  const int w = k >> 7, kk = (k >> 5) & 3, l4s = (k >> 3) & 3, es = k & 7;
  const float* row = U + (size_t)k * FH + j0;
#pragma unroll
  for (int i = 0; i < 8; ++i) {
    const int j = j0 + i;
    const int g2 = j >> 10, r = j & 1023;
    const int cgv = r >> 5, s = r & 31;
    const int nt = g2 * 2 + (s >> 4), l15 = s & 15;
    const int chunk = (((cgv * 8 + w) * 8 + nt) * 4 + kk) * 64 + l4s * 16 + l15;
    uf[(size_t)chunk * 8 + es] = (f16)row[i];
  }
}

// ---------------------------------------------------------------------------
// Wd (f32 [1024][128]) -> fp16 fragment chunks [nt 8][kk 32][lane 64][e 8]
__global__ void prep_Wd(const float* __restrict__ Wd, f16* __restrict__ wd) {
  const int c = blockIdx.x * 256 + threadIdx.x;       // 0..16383
  const int lane = c & 63, kk = (c >> 6) & 31, nt = c >> 11;
  const int k0 = kk * 32 + ((lane >> 4) << 3);
  const int v  = nt * 16 + (lane & 15);
  f16x8 o;
#pragma unroll
  for (int e = 0; e < 8; ++e) o[e] = (f16)Wd[(size_t)(k0 + e) * V + v];
  ((f16x8*)wd)[c] = o;
}

// ---------------------------------------------------------------------------
// tagged entry (16B): {h0h1, h2h3, tag, pad}; holds h[j..j+3] for batch b,
//   j = ws*128 + kk*32 + l4*8 + hf*4.
//   idx(bg,ws,l4,kk,hf,b16) = (((((bg*8+ws)*4+l4)*4+kk)*2+hf))*16 + b16
// Consumer lane (w,l4,l15): 8 entries at base + (kk*2+hf)*256B, lane
// stride 16B -> every load is 64x16B contiguous (fully coalesced).
__global__ __launch_bounds__(512, 2) void lstm_kernel(
    const int*   __restrict__ tok,    // [128][512]
    const float* __restrict__ embW,   // [128][4096]
    const f16x8* __restrict__ Ufrag,
    u32x4* hT0, u32x4* hT1,
    f16* __restrict__ st,             // states frag [t*8+bg][kc 128][m 16][e 8]
    int* ctrl)
{
  const int blk = blockIdx.x;
  const int tid = threadIdx.x;
  const int w = tid >> 6, lane = tid & 63;
  const int l15 = lane & 15, l4 = lane >> 4;

  int* initctr = ctrl;
  int* xcdcnt  = ctrl + 8;

  // 82560B (>80KB => 1 block/CU => all 256 blocks co-resident)
  __shared__ f16 zph[2][8][129][20];  // [parity][wave][n 128(+1)][m 16(+4)]
  __shared__ int s_bg, s_cg, s_fast;

  // ---- one-time election: discover placement, assign XCD-local roles ----
  const int myxcd = (int)(__builtin_amdgcn_s_getreg(6164) & 15); // HW_REG_XCC_ID
  if (tid == 0) {
    const int rank = __hip_atomic_fetch_add(&xcdcnt[myxcd & 7], 1,
                                            __ATOMIC_RELAXED, __HIP_MEMORY_SCOPE_AGENT);
    __hip_atomic_fetch_add(initctr, 1, __ATOMIC_RELEASE, __HIP_MEMORY_SCOPE_AGENT);
    int spins = 0;
    while (__hip_atomic_load(initctr, __ATOMIC_RELAXED, __HIP_MEMORY_SCOPE_AGENT) < 256) {
      __builtin_amdgcn_s_sleep(8);
      if (++spins > (1 << 15)) break;       // watchdog: never hang
    }
    const int total = __hip_atomic_load(initctr, __ATOMIC_ACQUIRE,
                                        __HIP_MEMORY_SCOPE_AGENT);
    int fast = (total >= 256) ? 1 : 0;
    for (int i = 0; i < 8; ++i)
      fast &= (__hip_atomic_load(&xcdcnt[i], __ATOMIC_RELAXED,
                                 __HIP_MEMORY_SCOPE_AGENT) == 32) ? 1 : 0;
    s_fast = fast;
    s_bg = fast ? (myxcd & 7) : (blk & 7);  // fast: bg-group == one XCD
    s_cg = fast ? rank        : (blk >> 3);
  }
  __syncthreads();
  const int FAST = s_fast;
  const int bg = s_bg, cg = s_cg;

  // persistent U fragments: wave w -> k in [w*128, w*128+128), n 0..127
  f16x8 Bf[8][4];
  {
    const f16x8* up = Ufrag + (size_t)(cg * 8 + w) * 2048;
#pragma unroll
    for (int nt = 0; nt < 8; ++nt)
#pragma unroll
      for (int kk = 0; kk < 4; ++kk)
        Bf[nt][kk] = up[(nt * 4 + kk) * 64 + lane];
  }

  // gate-phase assignment: one (batch-row, hcol) per thread
  const int m_g = tid >> 5;            // 0..15
  const int l_g = tid & 31;            // 0..31
  const int b_g = bg * 16 + m_g;
  const int j_g = cg * 32 + l_g;       // hcol this thread produces
  const int w_s = cg >> 2, kk_s = cg & 3, l4_s = l_g >> 3, hf_s = (l_g >> 2) & 1;
  const int pidx = ((((bg * 8 + w_s) * 4 + l4_s) * 4 + kk_s) * 2 + hf_s) * 16 + m_g;
  float c_st = 0.f, h_st = 0.f;

  // consumer: 8 coalesced tagged entries (offsets (kk*2+hf)*256B)
  const int cbase = ((((bg * 8 + w) * 4 + l4) * 4) * 2) * 16 + l15;

  const size_t stbase = (((size_t)(j_g >> 3)) * 16 + m_g) * 8 + (j_g & 7);

  for (int t = 0; t < T; ++t) {
    // prefetch xz gather (latency overlaps the poll)
    const int tk = tok[(size_t)b_g * T + t];
    const float* ew = embW + (size_t)tk * FH + j_g;
    const float x0 = ew[0], x1 = ew[1024], x2 = ew[2048], x3 = ew[3072];

    const u32 want = (u32)t;
    const u32x4* hb = ((t & 1) ? hT1 : hT0) + cbase;
    u32x4 e0, e1, e2, e3, e4, e5, e6, e7;

    // ---- poll tagged entries: ONE RT = sync + data (common case) ----
    {
      int spins = 0;
      for (;;) {
        asm volatile(
            "global_load_dwordx4 %0, %8, off sc0 sc1\n\t"
            "global_load_dwordx4 %1, %8, off offset:256 sc0 sc1\n\t"
            "global_load_dwordx4 %2, %8, off offset:512 sc0 sc1\n\t"
            "global_load_dwordx4 %3, %8, off offset:768 sc0 sc1\n\t"
            "global_load_dwordx4 %4, %8, off offset:1024 sc0 sc1\n\t"
            "global_load_dwordx4 %5, %8, off offset:1280 sc0 sc1\n\t"
            "global_load_dwordx4 %6, %8, off offset:1536 sc0 sc1\n\t"
            "global_load_dwordx4 %7, %8, off offset:1792 sc0 sc1\n\t"
            "s_waitcnt vmcnt(0)"
            : "=&v"(e0), "=&v"(e1), "=&v"(e2), "=&v"(e3),
              "=&v"(e4), "=&v"(e5), "=&v"(e6), "=&v"(e7)
            : "v"(hb)
            : "memory");
        const bool ok = (e0.z == want) & (e1.z == want) & (e2.z == want) &
                        (e3.z == want) & (e4.z == want) & (e5.z == want) &
                        (e6.z == want) & (e7.z == want);
        if (__all((int)ok)) break;
        if (++spins > (1 << 17)) break;     // watchdog: never hang
        if (spins > 8) __builtin_amdgcn_s_sleep(1);
      }
    }

    // A fragments: {e(kk,hf=0).xy, e(kk,hf=1).xy}
    f16x8 a0, a1, a2, a3;
    {
      u32x4 v0 = {e0.x, e0.y, e1.x, e1.y};
      u32x4 v1 = {e2.x, e2.y, e3.x, e3.y};
      u32x4 v2 = {e4.x, e4.y, e5.x, e5.y};
      u32x4 v3 = {e6.x, e6.y, e7.x, e7.y};
      a0 = __builtin_bit_cast(f16x8, v0);
      a1 = __builtin_bit_cast(f16x8, v1);
      a2 = __builtin_bit_cast(f16x8, v2);
      a3 = __builtin_bit_cast(f16x8, v3);
    }

    f32x4 acc[8];
#pragma unroll
    for (int nt = 0; nt < 8; ++nt) acc[nt] = (f32x4){0.f, 0.f, 0.f, 0.f};
#define MF(AH, KK)                                                                 \
  {                                                                                \
    _Pragma("unroll")                                                              \
    for (int nt = 0; nt < 8; ++nt)                                                 \
      acc[nt] = __builtin_amdgcn_mfma_f32_16x16x32_f16(AH, Bf[nt][KK], acc[nt], 0, 0, 0); \
  }
    MF(a0, 0) MF(a1, 1) MF(a2, 2) MF(a3, 3)
#undef MF

    // partial z -> LDS (f16, parity buffers). D: col(n)=l15, row(m)=l4*4+r
    const int par = t & 1;
#pragma unroll
    for (int nt = 0; nt < 8; ++nt) {
      f16x4 v4;
#pragma unroll
      for (int r = 0; r < 4; ++r) v4[r] = (f16)acc[nt][r];
      *(f16x4*)&zph[par][w][nt * 16 + l15][l4 * 4] = v4;
    }
    __syncthreads();   // the ONLY barrier per step (RAW for gate reads)

    // ---- gate phase ----
    float z0 = x0, z1 = x1, z2 = x2, z3 = x3;
#pragma unroll
    for (int q = 0; q < 8; ++q) {
      z0 += (float)zph[par][q][l_g][m_g];
      z1 += (float)zph[par][q][32 + l_g][m_g];
      z2 += (float)zph[par][q][64 + l_g][m_g];
      z3 += (float)zph[par][q][96 + l_g][m_g];
    }
    const float ig = fast_sigmoid(z0);
    const float fg = fast_sigmoid(z1);
    const float gg = fast_tanh(z2);
    const float og = fast_sigmoid(z3);
    const float cn = fg * c_st + ig * gg;
    const float hn = og * fast_tanh(cn);
    if (tk != 0) { c_st = cn; h_st = hn; }   // masked hold in exact f32

    const f16 hv = (f16)h_st;

    // pack 4 neighbors' h + tag(t+1) into one 16B entry (2 shfls, r7-proven)
    const u32 hbits = (u32)__builtin_bit_cast(unsigned short, hv);
    const u32 n1  = (u32)__shfl_xor((int)hbits, 1, 64);
    const u32 u01 = hbits | (n1 << 16);
    const u32 u23 = (u32)__shfl_xor((int)u01, 2, 64);
    if ((l_g & 3) == 0) {
      u32x4 val = {u01, u23, (u32)(t + 1), 0u};
      u32x4* dst = ((t & 1) ? hT0 : hT1) + pidx;   // h_{t+1} -> buffer[(t+1)&1]
      if (FAST)                                    // plain: dirty in XCD L2
        asm volatile("global_store_dwordx4 %0, %1, off"
                     :: "v"(dst), "v"(val) : "memory");
      else
        asm volatile("global_store_dwordx4 %0, %1, off sc0 sc1"
                     :: "v"(dst), "v"(val) : "memory");
    }

    // st store AFTER the signal: off the critical chain
    st[(size_t)(t * 8 + bg) * 16384 + stbase] = hv;
  }
}

// ---------------------------------------------------------------------------
// logits + softmax: row-groups rho = t*8+bg (4096 of 16 rows), 16 per block
__global__ __launch_bounds__(512, 2) void logits_kernel(
    const uint4* __restrict__ st, const uint4* __restrict__ wd,
    const float* __restrict__ bd, float* __restrict__ out)
{
  __shared__ f16 As[256 * 64];   // [rb 16][kc 8][m 16][e 8] = 32KB
  __shared__ f16 Bs[64 * 128];   // [nt 8][kkl 2][lane 64][e 8] = 16KB
  const int tid = threadIdx.x;
  const int w = tid >> 6, lane = tid & 63;
  const int l15 = lane & 15, l4 = lane >> 4;
  const int rblk0 = blockIdx.x * 16;

  f32x4 acc[2][8];
#pragma unroll
  for (int rb = 0; rb < 2; ++rb)
#pragma unroll
    for (int nt = 0; nt < 8; ++nt) acc[rb][nt] = (f32x4){0.f, 0.f, 0.f, 0.f};

  for (int ph = 0; ph < 16; ++ph) {        // k = ph*64 .. +64
    __syncthreads();
#pragma unroll
    for (int i = 0; i < 4; ++i) {          // A: 16 rb x 8 kc x 16 m chunks
      const int cc = tid * 4 + i;
      const int rb = cc >> 7, kc = (cc >> 4) & 7, m = cc & 15;
      ((uint4*)As)[cc] = st[((size_t)(rblk0 + rb) * 128 + ph * 8 + kc) * 16 + m];
    }
#pragma unroll
    for (int i = 0; i < 2; ++i) {          // B: 8 nt x 2 kkl x 64 chunks
      const int cc = tid * 2 + i;
      const int lc = cc & 63, kkl = (cc >> 6) & 1, nt = cc >> 7;
      ((uint4*)Bs)[cc] = wd[((size_t)nt * 32 + ph * 2 + kkl) * 64 + lc];
    }
    __syncthreads();
#pragma unroll
    for (int kkl = 0; kkl < 2; ++kkl)
#pragma unroll
      for (int rb = 0; rb < 2; ++rb) {
        const f16x8 a = ((const f16x8*)As)[((w * 2 + rb) * 8 + kkl * 4 + l4) * 16 + l15];
#pragma unroll
        for (int nt = 0; nt < 8; ++nt)
          acc[rb][nt] = __builtin_amdgcn_mfma_f32_16x16x32_f16(
              a, ((const f16x8*)Bs)[(nt * 2 + kkl) * 64 + lane], acc[rb][nt], 0, 0, 0);
      }
  }

  // epilogue: +bd, row softmax (row over 16 lanes x 8 nt), write f32
#pragma unroll
  for (int rb = 0; rb < 2; ++rb) {
    float mx[4] = {-3.0e38f, -3.0e38f, -3.0e38f, -3.0e38f};
#pragma unroll
    for (int nt = 0; nt < 8; ++nt) {
      const float bv = bd[nt * 16 + l15];
#pragma unroll
      for (int r = 0; r < 4; ++r) {
        acc[rb][nt][r] += bv;
        mx[r] = fmaxf(mx[r], acc[rb][nt][r]);
      }
    }
#pragma unroll
    for (int d = 1; d < 16; d <<= 1)
#pragma unroll
      for (int r = 0; r < 4; ++r) mx[r] = fmaxf(mx[r], __shfl_xor(mx[r], d, 64));
    float sm[4] = {0.f, 0.f, 0.f, 0.f};
#pragma unroll
    for (int nt = 0; nt < 8; ++nt)
#pragma unroll
      for (int r = 0; r < 4; ++r) {
        const float p = expf(acc[rb][nt][r] - mx[r]);
        acc[rb][nt][r] = p;
        sm[r] += p;
      }
#pragma unroll
    for (int d = 1; d < 16; d <<= 1)
#pragma unroll
      for (int r = 0; r < 4; ++r) sm[r] += __shfl_xor(sm[r], d, 64);
#pragma unroll
    for (int r = 0; r < 4; ++r) {
      const float inv = 1.f / sm[r];
      const int rg = (rblk0 + w * 2 + rb) * 16 + l4 * 4 + r;  // = t*128 + b
      const int bb = rg & 127, tt = rg >> 7;
      float* op = out + ((size_t)bb * T + tt) * V;
#pragma unroll
      for (int nt = 0; nt < 8; ++nt) op[nt * 16 + l15] = acc[rb][nt][r] * inv;
    }
  }
}

// ---------------------------------------------------------------------------
extern "C" void kernel_launch(void* const* d_in, const int* in_sizes, int n_in,
                              void* d_out, int out_size, void* d_ws, size_t ws_size,
                              hipStream_t stream) {
  const int*   tokens = (const int*)d_in[0];
  const float* emb    = (const float*)d_in[1];
  const float* W      = (const float*)d_in[2];
  const float* U      = (const float*)d_in[3];
  const float* bias   = (const float*)d_in[4];
  const float* Wd     = (const float*)d_in[5];
  const float* bd     = (const float*)d_in[6];
  float* out = (float*)d_out;
  char* ws = (char*)d_ws;

  if (ws_size < WS_NEED) {
    fprintf(stderr, "kernel_launch: ws too small: %zu < %zu\n", ws_size, WS_NEED);
    return;
  }

  int*   ctrl = (int*)(ws + OFF_CTRL);
  u32x4* hT0  = (u32x4*)(ws + OFF_HT0);
  u32x4* hT1  = (u32x4*)(ws + OFF_HT1);
  float* embW = (float*)(ws + OFF_EMBW);
  f16*   uf   = (f16*)(ws + OFF_UF);
  f16*   wdf  = (f16*)(ws + OFF_WD);
  f16*   st   = (f16*)(ws + OFF_ST);

  // zero ctrl (election) + both tagged parity buffers every launch/replay
  (void)hipMemsetAsync(ws, 0, OFF_EMBW, stream);

  prep_embW<<<256, 256, 0, stream>>>(emb, W, bias, embW);
  prep_U<<<2048, 256, 0, stream>>>(U, uf);
  prep_Wd<<<64, 256, 0, stream>>>(Wd, wdf);

  lstm_kernel<<<256, 512, 0, stream>>>(tokens, embW, (const f16x8*)uf,
                                       hT0, hT1, st, ctrl);

  logits_kernel<<<256, 512, 0, stream>>>((const uint4*)st, (const uint4*)wdf,
                                         bd, out);
}

// Round 15
// 1063.277 us; speedup vs baseline: 1.1124x; 1.1124x over previous
//
#include <hip/hip_runtime.h>
#include <stdio.h>

// ---------------------------------------------------------------------------
// Masked-LSTM LM:  out = softmax(states @ Wd + bd)
//
// Round-15 = r13 (best: flags + coalesced untagged entries) +
//  * k-split-4 x n-split-2: wave (kg=w&3, ng=w>>2) covers k in
//    [kg*256,+256) (8 kks) x n in [ng*64,+64) (4 nts). Same 32 MFMA/wave;
//    partials per output halve (8->4): gate reads 16 (was 32) scalar f16,
//    zph writes 4 (was 8) f16x4. Consumer: 8 coalesced dwordx4 loads
//    (offset kk*256B, lane stride 16B) - one RT batch.
//  * Hot-spin flag poll (no s_sleep until watchdog): sweep = 4B/lane,
//    discovery granularity = sweep RT, not 64-cy sleep quanta.
//  * Flags one per (producer block, wave): consumer wave polls 64 flags,
//    one per lane.
//  * Protocol (r12/r13-proven): producer plain stores -> dirty in local
//    XCD L2; consumer sc0 sc1 loads bypass L1, served fresh by L2.
//    Producer per-wave vmcnt(0) -> flag store. ONE block barrier/step.
//  * Canary: absmax must stay ~6.103516e-5.
// ---------------------------------------------------------------------------

typedef _Float16 f16;
typedef f16 f16x8 __attribute__((ext_vector_type(8)));
typedef f16 f16x4 __attribute__((ext_vector_type(4)));
typedef float f32x4 __attribute__((ext_vector_type(4)));
typedef unsigned int u32;
typedef u32 u32x4 __attribute__((ext_vector_type(4)));

static constexpr int V = 128, E = 256, H = 1024, NB = 128, T = 512, FH = 4096;

// workspace layout (bytes)
static constexpr size_t OFF_CTRL = 0;        // [0]=initctr, [8..15]=xcdcnt, [1024..]=flags[2048]
static constexpr size_t SZ_CTRL  = 16384;
static constexpr size_t OFF_HB0  = SZ_CTRL;  // entries [bg8][kg4][l4 4][kk8][b16] f16x8
static constexpr size_t SZ_HB    = (size_t)16384 * 16;         // 256 KB
static constexpr size_t OFF_HB1  = OFF_HB0 + SZ_HB;
static constexpr size_t OFF_EMBW = OFF_HB1 + SZ_HB;            // 2 MB f32
static constexpr size_t SZ_EMBW  = (size_t)V * FH * 4;
static constexpr size_t OFF_UF   = OFF_EMBW + SZ_EMBW;         // 8 MB f16
static constexpr size_t SZ_UF    = (size_t)H * FH * 2;
static constexpr size_t OFF_WD   = OFF_UF + SZ_UF;             // 256 KB f16
static constexpr size_t SZ_WD    = (size_t)H * V * 2;
static constexpr size_t OFF_ST   = OFF_WD + SZ_WD;             // 128 MB f16
static constexpr size_t SZ_ST    = (size_t)NB * T * H * 2;
static constexpr size_t WS_NEED  = OFF_ST + SZ_ST;             // ~139 MB

// ---------------------------------------------------------------------------
__device__ __forceinline__ float fast_sigmoid(float x) {
  return __builtin_amdgcn_rcpf(1.f + __expf(-x));
}
__device__ __forceinline__ float fast_tanh(float x) {
  const float e = __expf(2.f * x);
  return (e - 1.f) * __builtin_amdgcn_rcpf(e + 1.f);
}

// ---------------------------------------------------------------------------
// embW[v][j] = b[j] + sum_e emb[v][e] * W[e][j]
__global__ void prep_embW(const float* __restrict__ emb, const float* __restrict__ W,
                          const float* __restrict__ bias, float* __restrict__ embW) {
  const int j  = blockIdx.x * 16 + (threadIdx.x & 15);
  const int vg = threadIdx.x >> 4;
  float a[8];
  const float bj = bias[j];
#pragma unroll
  for (int r = 0; r < 8; ++r) a[r] = bj;
  for (int e = 0; e < E; ++e) {
    const float wv = W[(size_t)e * FH + j];
#pragma unroll
    for (int r = 0; r < 8; ++r) a[r] += emb[(size_t)(vg * 8 + r) * E + e] * wv;
  }
#pragma unroll
  for (int r = 0; r < 8; ++r) embW[(size_t)(vg * 8 + r) * FH + j] = a[r];
}

// ---------------------------------------------------------------------------
// U (f32 [1024][4096]) -> fp16 B-fragment chunks, coalesced reads.
// Wave (kg=w&3, ng=w>>2): Bf[nt][kk] = up[(nt*8+kk)*64 + lane], where
//   k = kg*256 + kk*32 + (lane>>4)*8 + e
//   n = ng*64 + nt*16 + (lane&15);  ucol = (n>>5)*1024 + cg*32 + (n&31)
__global__ void prep_U(const float* __restrict__ U, f16* __restrict__ uf) {
  const int q  = blockIdx.x * 256 + threadIdx.x;      // 0..524287
  const int k  = q >> 9;
  const int j0 = (q & 511) * 8;
  const int kg = k >> 8, kk = (k >> 5) & 7, l4s = (k >> 3) & 3, es = k & 7;
  const float* row = U + (size_t)k * FH + j0;
#pragma unroll
  for (int i = 0; i < 8; ++i) {
    const int j = j0 + i;
    const int g = j >> 10, cg = (j >> 5) & 31, s = j & 31;
    const int n = g * 32 + s;
    const int ng = n >> 6, nt = (n >> 4) & 3, l15 = n & 15;
    const int w = ng * 4 + kg;
    const int chunk = ((cg * 8 + w) * 4 + nt) * 8 + kk;
    uf[((size_t)chunk * 64 + l4s * 16 + l15) * 8 + es] = (f16)row[i];
  }
}

// ---------------------------------------------------------------------------
// Wd (f32 [1024][128]) -> fp16 fragment chunks [nt 8][kk 32][lane 64][e 8]
__global__ void prep_Wd(const float* __restrict__ Wd, f16* __restrict__ wd) {
  const int c = blockIdx.x * 256 + threadIdx.x;       // 0..16383
  const int lane = c & 63, kk = (c >> 6) & 31, nt = c >> 11;
  const int k0 = kk * 32 + ((lane >> 4) << 3);
  const int v  = nt * 16 + (lane & 15);
  f16x8 o;
#pragma unroll
  for (int e = 0; e < 8; ++e) o[e] = (f16)Wd[(size_t)(k0 + e) * V + v];
  ((f16x8*)wd)[c] = o;
}

// ---------------------------------------------------------------------------
// entry (16B, f16x8): h[j..j+7], j = kg*256 + kk*32 + l4*8, batch b.
//   idx(bg,kg,l4,kk,b16) = (((bg*4 + kg)*4 + l4)*8 + kk)*16 + b16
// Producer block cg: kg=cg>>3, kk=cg&7, l4=l_g>>3 (8 threads/entry).
// Consumer wave (kg): 8 loads at base + kk*256B, lane stride 16B.
// flags idx(bg,cg,pw) = (bg*4 + (cg>>3))*64 + (cg&7)*8 + pw; value t+1.
__global__ __launch_bounds__(512, 2) void lstm_kernel(
    const int*   __restrict__ tok,    // [128][512]
    const float* __restrict__ embW,   // [128][4096]
    const f16x8* __restrict__ Ufrag,
    u32x4* hB0, u32x4* hB1,
    f16* __restrict__ st,             // states frag [t*8+bg][kc 128][m 16][e 8]
    int* ctrl)
{
  const int blk = blockIdx.x;
  const int tid = threadIdx.x;
  const int w = tid >> 6, lane = tid & 63;
  const int l15 = lane & 15, l4 = lane >> 4;
  const int kg = w & 3, ng = w >> 2;

  int* initctr = ctrl;
  int* xcdcnt  = ctrl + 8;
  int* flags   = ctrl + 1024;         // [bg 8][kg 4][c8 8][pw 8]

  // 82560B (>80KB => 1 block/CU => all 256 blocks co-resident).
  // Only q=0..3 planes used (k-split-4); extra planes keep the LDS pin.
  __shared__ f16 zph[2][8][129][20];
  __shared__ int s_bg, s_cg, s_fast;

  // ---- one-time election: discover placement, assign XCD-local roles ----
  const int myxcd = (int)(__builtin_amdgcn_s_getreg(6164) & 15); // HW_REG_XCC_ID
  if (tid == 0) {
    const int rank = __hip_atomic_fetch_add(&xcdcnt[myxcd & 7], 1,
                                            __ATOMIC_RELAXED, __HIP_MEMORY_SCOPE_AGENT);
    __hip_atomic_fetch_add(initctr, 1, __ATOMIC_RELEASE, __HIP_MEMORY_SCOPE_AGENT);
    int spins = 0;
    while (__hip_atomic_load(initctr, __ATOMIC_RELAXED, __HIP_MEMORY_SCOPE_AGENT) < 256) {
      __builtin_amdgcn_s_sleep(8);
      if (++spins > (1 << 15)) break;       // watchdog: never hang
    }
    const int total = __hip_atomic_load(initctr, __ATOMIC_ACQUIRE,
                                        __HIP_MEMORY_SCOPE_AGENT);
    int fast = (total >= 256) ? 1 : 0;
    for (int i = 0; i < 8; ++i)
      fast &= (__hip_atomic_load(&xcdcnt[i], __ATOMIC_RELAXED,
                                 __HIP_MEMORY_SCOPE_AGENT) == 32) ? 1 : 0;
    s_fast = fast;
    s_bg = fast ? (myxcd & 7) : (blk & 7);  // fast: bg-group == one XCD
    s_cg = fast ? rank        : (blk >> 3);
  }
  __syncthreads();
  const int FAST = s_fast;
  const int bg = s_bg, cg = s_cg;

  // persistent U fragments: wave (kg,ng) -> k [kg*256,+256), n [ng*64,+64)
  f16x8 Bf[4][8];
  {
    const f16x8* up = Ufrag + (size_t)(cg * 8 + w) * 2048;
#pragma unroll
    for (int nt = 0; nt < 4; ++nt)
#pragma unroll
      for (int kk = 0; kk < 8; ++kk)
        Bf[nt][kk] = up[(nt * 8 + kk) * 64 + lane];
  }

  // gate-phase assignment: one (batch-row, hcol) per thread
  const int m_g = tid >> 5;            // 0..15
  const int l_g = tid & 31;            // 0..31
  const int b_g = bg * 16 + m_g;
  const int j_g = cg * 32 + l_g;       // hcol this thread produces
  const int kg_s = cg >> 3, kk_s = cg & 7, l4_s = l_g >> 3;
  const int pidx = (((bg * 4 + kg_s) * 4 + l4_s) * 8 + kk_s) * 16 + m_g;
  // this wave's producer flag
  int* pflag = flags + (bg * 4 + kg_s) * 64 + kk_s * 8 + w;
  float c_st = 0.f, h_st = 0.f;

  // consumer: 8 coalesced entries (kk 0..7 at offset kk*256B); 64 flags
  const int cbase = (((bg * 4 + kg) * 4 + l4) * 8) * 16 + l15;
  const int* fpoll = flags + (bg * 4 + kg) * 64 + lane;

  const size_t stbase = (((size_t)(j_g >> 3)) * 16 + m_g) * 8 + (j_g & 7);

  for (int t = 0; t < T; ++t) {
    // prefetch xz gather (latency overlaps the poll)
    const int tk = tok[(size_t)b_g * T + t];
    const float* ew = embW + (size_t)tk * FH + j_g;
    const float x0 = ew[0], x1 = ew[1024], x2 = ew[2048], x3 = ew[3072];

    // ---- flag poll: hot spin, sc1 loads served fresh by local L2 ----
    {
      int fv, spins = 0;
      for (;;) {
        asm volatile("global_load_dword %0, %1, off sc0 sc1\n\t"
                     "s_waitcnt vmcnt(0)"
                     : "=v"(fv) : "v"(fpoll) : "memory");
        if (__all(fv >= t)) break;
        if (++spins > (1 << 17)) break;     // watchdog: never hang
        if (spins > 2048) __builtin_amdgcn_s_sleep(1);
      }
    }

    // ---- data: ONE coalesced sc1 batch (fresh by flag ordering) ----
    const u32x4* hb = ((t & 1) ? hB1 : hB0) + cbase;
    u32x4 e0, e1, e2, e3, e4, e5, e6, e7;
    asm volatile(
        "global_load_dwordx4 %0, %8, off sc0 sc1\n\t"
        "global_load_dwordx4 %1, %8, off offset:256 sc0 sc1\n\t"
        "global_load_dwordx4 %2, %8, off offset:512 sc0 sc1\n\t"
        "global_load_dwordx4 %3, %8, off offset:768 sc0 sc1\n\t"
        "global_load_dwordx4 %4, %8, off offset:1024 sc0 sc1\n\t"
        "global_load_dwordx4 %5, %8, off offset:1280 sc0 sc1\n\t"
        "global_load_dwordx4 %6, %8, off offset:1536 sc0 sc1\n\t"
        "global_load_dwordx4 %7, %8, off offset:1792 sc0 sc1\n\t"
        "s_waitcnt vmcnt(0)"
        : "=&v"(e0), "=&v"(e1), "=&v"(e2), "=&v"(e3),
          "=&v"(e4), "=&v"(e5), "=&v"(e6), "=&v"(e7)
        : "v"(hb)
        : "memory");
    const f16x8 a0 = __builtin_bit_cast(f16x8, e0);
    const f16x8 a1 = __builtin_bit_cast(f16x8, e1);
    const f16x8 a2 = __builtin_bit_cast(f16x8, e2);
    const f16x8 a3 = __builtin_bit_cast(f16x8, e3);
    const f16x8 a4 = __builtin_bit_cast(f16x8, e4);
    const f16x8 a5 = __builtin_bit_cast(f16x8, e5);
    const f16x8 a6 = __builtin_bit_cast(f16x8, e6);
    const f16x8 a7 = __builtin_bit_cast(f16x8, e7);

    f32x4 acc[4];
#pragma unroll
    for (int nt = 0; nt < 4; ++nt) acc[nt] = (f32x4){0.f, 0.f, 0.f, 0.f};
#define MF(AH, KK)                                                                 \
  {                                                                                \
    _Pragma("unroll")                                                              \
    for (int nt = 0; nt < 4; ++nt)                                                 \
      acc[nt] = __builtin_amdgcn_mfma_f32_16x16x32_f16(AH, Bf[nt][KK], acc[nt], 0, 0, 0); \
  }
    MF(a0, 0) MF(a1, 1) MF(a2, 2) MF(a3, 3)
    MF(a4, 4) MF(a5, 5) MF(a6, 6) MF(a7, 7)
#undef MF

    // partial z -> LDS (f16, parity). D: col(n)=l15, row(m)=l4*4+r
    const int par = t & 1;
#pragma unroll
    for (int nt = 0; nt < 4; ++nt) {
      f16x4 v4;
#pragma unroll
      for (int r = 0; r < 4; ++r) v4[r] = (f16)acc[nt][r];
      *(f16x4*)&zph[par][kg][ng * 64 + nt * 16 + l15][l4 * 4] = v4;
    }
    __syncthreads();   // the ONLY barrier per step (RAW for gate reads)

    // ---- gate phase: 4 partials per gate (16 scalar LDS reads) ----
    float z0 = x0, z1 = x1, z2 = x2, z3 = x3;
#pragma unroll
    for (int q = 0; q < 4; ++q) {
      z0 += (float)zph[par][q][l_g][m_g];
      z1 += (float)zph[par][q][32 + l_g][m_g];
      z2 += (float)zph[par][q][64 + l_g][m_g];
      z3 += (float)zph[par][q][96 + l_g][m_g];
    }
    const float ig = fast_sigmoid(z0);
    const float fg = fast_sigmoid(z1);
    const float gg = fast_tanh(z2);
    const float og = fast_sigmoid(z3);
    const float cn = fg * c_st + ig * gg;
    const float hn = og * fast_tanh(cn);
    if (tk != 0) { c_st = cn; h_st = hn; }   // masked hold in exact f32

    const f16 hv = (f16)h_st;

    // pack 8 neighbors' h into one f16x8 entry (4 shfls, r8/r13-verified)
    const u32 hbits = (u32)__builtin_bit_cast(unsigned short, hv);
    const u32 p  = hbits | ((u32)__shfl_xor((int)hbits, 1, 64) << 16);
    const u32 q2 = (u32)__shfl_xor((int)p, 2, 64);
    const u32 r2 = (u32)__shfl_xor((int)p, 4, 64);
    const u32 s2 = (u32)__shfl_xor((int)q2, 4, 64);
    if ((l_g & 7) == 0) {
      u32x4 val = {p, q2, r2, s2};
      u32x4* dst = ((t & 1) ? hB0 : hB1) + pidx;   // h_{t+1} -> buffer[(t+1)&1]
      if (FAST)                                    // plain: dirty in XCD L2
        asm volatile("global_store_dwordx4 %0, %1, off"
                     :: "v"(dst), "v"(val) : "memory");
      else
        asm volatile("global_store_dwordx4 %0, %1, off sc0 sc1"
                     :: "v"(dst), "v"(val) : "memory");
    }

    // per-wave release: drain this wave's entry stores, then epoch flag
    asm volatile("s_waitcnt vmcnt(0)" ::: "memory");
    if (lane == 0) {
      const int tv = t + 1;
      if (FAST)
        asm volatile("global_store_dword %0, %1, off"
                     :: "v"(pflag), "v"(tv) : "memory");
      else
        asm volatile("global_store_dword %0, %1, off sc0 sc1"
                     :: "v"(pflag), "v"(tv) : "memory");
    }

    // st store AFTER the signal: off the critical chain
    st[(size_t)(t * 8 + bg) * 16384 + stbase] = hv;
  }
}

// ---------------------------------------------------------------------------
// logits + softmax: row-groups rho = t*8+bg (4096 of 16 rows), 16 per block
__global__ __launch_bounds__(512, 2) void logits_kernel(
    const uint4* __restrict__ st, const uint4* __restrict__ wd,
    const float* __restrict__ bd, float* __restrict__ out)
{
  __shared__ f16 As[256 * 64];   // [rb 16][kc 8][m 16][e 8] = 32KB
  __shared__ f16 Bs[64 * 128];   // [nt 8][kkl 2][lane 64][e 8] = 16KB
  const int tid = threadIdx.x;
  const int w = tid >> 6, lane = tid & 63;
  const int l15 = lane & 15, l4 = lane >> 4;
  const int rblk0 = blockIdx.x * 16;

  f32x4 acc[2][8];
#pragma unroll
  for (int rb = 0; rb < 2; ++rb)
#pragma unroll
    for (int nt = 0; nt < 8; ++nt) acc[rb][nt] = (f32x4){0.f, 0.f, 0.f, 0.f};

  for (int ph = 0; ph < 16; ++ph) {        // k = ph*64 .. +64
    __syncthreads();
#pragma unroll
    for (int i = 0; i < 4; ++i) {          // A: 16 rb x 8 kc x 16 m chunks
      const int cc = tid * 4 + i;
      const int rb = cc >> 7, kc = (cc >> 4) & 7, m = cc & 15;
      ((uint4*)As)[cc] = st[((size_t)(rblk0 + rb) * 128 + ph * 8 + kc) * 16 + m];
    }
#pragma unroll
    for (int i = 0; i < 2; ++i) {          // B: 8 nt x 2 kkl x 64 chunks
      const int cc = tid * 2 + i;
      const int lc = cc & 63, kkl = (cc >> 6) & 1, nt = cc >> 7;
      ((uint4*)Bs)[cc] = wd[((size_t)nt * 32 + ph * 2 + kkl) * 64 + lc];
    }
    __syncthreads();
#pragma unroll
    for (int kkl = 0; kkl < 2; ++kkl)
#pragma unroll
      for (int rb = 0; rb < 2; ++rb) {
        const f16x8 a = ((const f16x8*)As)[((w * 2 + rb) * 8 + kkl * 4 + l4) * 16 + l15];
#pragma unroll
        for (int nt = 0; nt < 8; ++nt)
          acc[rb][nt] = __builtin_amdgcn_mfma_f32_16x16x32_f16(
              a, ((const f16x8*)Bs)[(nt * 2 + kkl) * 64 + lane], acc[rb][nt], 0, 0, 0);
      }
  }

  // epilogue: +bd, row softmax (row over 16 lanes x 8 nt), write f32
#pragma unroll
  for (int rb = 0; rb < 2; ++rb) {
    float mx[4] = {-3.0e38f, -3.0e38f, -3.0e38f, -3.0e38f};
#pragma unroll
    for (int nt = 0; nt < 8; ++nt) {
      const float bv = bd[nt * 16 + l15];
#pragma unroll
      for (int r = 0; r < 4; ++r) {
        acc[rb][nt][r] += bv;
        mx[r] = fmaxf(mx[r], acc[rb][nt][r]);
      }
    }
#pragma unroll
    for (int d = 1; d < 16; d <<= 1)
#pragma unroll
      for (int r = 0; r < 4; ++r) mx[r] = fmaxf(mx[r], __shfl_xor(mx[r], d, 64));
    float sm[4] = {0.f, 0.f, 0.f, 0.f};
#pragma unroll
    for (int nt = 0; nt < 8; ++nt)
#pragma unroll
      for (int r = 0; r < 4; ++r) {
        const float p = expf(acc[rb][nt][r] - mx[r]);
        acc[rb][nt][r] = p;
        sm[r] += p;
      }
#pragma unroll
    for (int d = 1; d < 16; d <<= 1)
#pragma unroll
      for (int r = 0; r < 4; ++r) sm[r] += __shfl_xor(sm[r], d, 64);
#pragma unroll
    for (int r = 0; r < 4; ++r) {
      const float inv = 1.f / sm[r];
      const int rg = (rblk0 + w * 2 + rb) * 16 + l4 * 4 + r;  // = t*128 + b
      const int bb = rg & 127, tt = rg >> 7;
      float* op = out + ((size_t)bb * T + tt) * V;
#pragma unroll
      for (int nt = 0; nt < 8; ++nt) op[nt * 16 + l15] = acc[rb][nt][r] * inv;
    }
  }
}

// ---------------------------------------------------------------------------
extern "C" void kernel_launch(void* const* d_in, const int* in_sizes, int n_in,
                              void* d_out, int out_size, void* d_ws, size_t ws_size,
                              hipStream_t stream) {
  const int*   tokens = (const int*)d_in[0];
  const float* emb    = (const float*)d_in[1];
  const float* W      = (const float*)d_in[2];
  const float* U      = (const float*)d_in[3];
  const float* bias   = (const float*)d_in[4];
  const float* Wd     = (const float*)d_in[5];
  const float* bd     = (const float*)d_in[6];
  float* out = (float*)d_out;
  char* ws = (char*)d_ws;

  if (ws_size < WS_NEED) {
    fprintf(stderr, "kernel_launch: ws too small: %zu < %zu\n", ws_size, WS_NEED);
    return;
  }

  int*   ctrl = (int*)(ws + OFF_CTRL);
  u32x4* hB0  = (u32x4*)(ws + OFF_HB0);
  u32x4* hB1  = (u32x4*)(ws + OFF_HB1);
  float* embW = (float*)(ws + OFF_EMBW);
  f16*   uf   = (f16*)(ws + OFF_UF);
  f16*   wdf  = (f16*)(ws + OFF_WD);
  f16*   st   = (f16*)(ws + OFF_ST);

  // zero ctrl (election + flags) and both entry parity buffers every launch
  (void)hipMemsetAsync(ws, 0, OFF_EMBW, stream);

  prep_embW<<<256, 256, 0, stream>>>(emb, W, bias, embW);
  prep_U<<<2048, 256, 0, stream>>>(U, uf);
  prep_Wd<<<64, 256, 0, stream>>>(Wd, wdf);

  lstm_kernel<<<256, 512, 0, stream>>>(tokens, embW, (const f16x8*)uf,
                                       hB0, hB1, st, ctrl);

  logits_kernel<<<256, 512, 0, stream>>>((const uint4*)st, (const uint4*)wdf,
                                         bd, out);
}